// Round 17
// baseline (27.703 us; speedup 1.0000x reference)
//
#include <hip/hip_runtime.h>
#include <hip/hip_bf16.h>
#include <cstdint>

// ProkBertAttention: sliding-window (+-64) attention with RoPE.
// B=4, S=2048, H=12, D=64. fp32 in/out, bf16 MFMA compute.
// Mask input (d_in[3]) ignored: band structure computed analytically.
//
// Round 17 = round 16 (best: 26.62us) + 2-deep V-staging pipeline.
// r16 proved 6 chains/CU works once staging is spill-proof; its cost is
// exposed serial load latency. V jobs are 16 regs -> 2-deep fits the
// 64-VGPR cap: job-0 loads issued BEFORE bar2 (global loads are LDS-free,
// legal pre-barrier; hide under straggler wait), then issue j1 / store j0 /
// issue j2 / store j1 / store j2. K staging stays strictly serial (2-deep
// K = 64+ live regs, would spill). Everything else byte-identical to r16.
// Ledger: r16 26.62 (best, 6-chain + serial staging); r12 27.20; setprio
// neutral (r15); decomposition 35.3 (r14); (256,6) mis-compiles (r8/r11).

typedef short bf16x8 __attribute__((ext_vector_type(8)));
typedef float f32x4  __attribute__((ext_vector_type(4)));
typedef uint32_t u32x4 __attribute__((ext_vector_type(4)));

#define SLEN   2048
#define NHEAD  12
#define NBATCH 4
#define HD     64
#define WHALF  64
#define QT     64          // queries per block (4 waves x 16)
#define KROWS  192         // QT + 2*WHALF
#define NKC    9           // per-wave key chunks (144-key span)
#define VST    68          // V-pair row stride in dwords
#define VROWS  96          // key-pairs (max kp read = 95: kb=4 lo-only)
// scale * log2(e) = (1/8) * 1.4426950408889634 (scores in log2 units)
#define QSCALE 0.18033688011112042f

// Phase 1: sbuf holds K bf16 [192][64] (24,576 B), 16B-chunk XOR (c^(rr&7)).
// Phase 2: sbuf holds V key-paired u32 [96][68] (26,112 B), cell[kp][d] =
//          (bf16 V[2kp][d], V[2kp+1][d]).
// LDS alloc = 26,112 B; 6 blocks/CU (156,672 <= 163,840) at VGPR <= 64.

__device__ __forceinline__ uint32_t cvt_pk(float lo, float hi) {
    // dst[15:0] = bf16(lo), dst[31:16] = bf16(hi); RNE (gfx950)
    uint32_t r;
    asm("v_cvt_pk_bf16_f32 %0, %1, %2" : "=v"(r) : "v"(lo), "v"(hi));
    return r;
}

__global__ __launch_bounds__(256, 8) void prokbert_attn(
        const float* __restrict__ qkv, const float* __restrict__ cosT,
        const float* __restrict__ sinT, float* __restrict__ out)
{
    __shared__ __align__(16) uint32_t sbuf[VROWS * VST];
    short* sKp = (short*)sbuf;

    const int tid = threadIdx.x;

    // ---- XCD-aware block swizzle (1536 blocks = 8 XCDs x 192, bijective) ----
    const int bid = blockIdx.x;
    const int gid = (bid & 7) * 192 + (bid >> 3);
    const int qt = gid & 31;          // 32 q-tiles per (b,h)
    const int hh = gid >> 5;          // 0..47 = b*12 + h
    const int h = hh % NHEAD, b = hh / NHEAD;

    const int q0 = qt * QT;
    const int kstart = q0 - WHALF;

    const int wv = tid >> 6;
    const int lane = tid & 63;
    const int r = lane & 15, g = lane >> 4;
    const int rx = r & 7;
    const int qrow = q0 + wv * 16 + r;

    // ========== phase 1: K staging, 3 jobs, STRICTLY SERIAL ==========
    // job (rr, c4) owns d = c4*8..+7 AND +32; rr = rrb + it*64.
    const int rrb = tid >> 2, c4 = tid & 3, d0 = c4 * 8;

    #pragma unroll
    for (int it = 0; it < 3; ++it) {
        const int rr = rrb + it * 64;
        const int s = kstart + rr;
        u32x4 klo = {0, 0, 0, 0}, khi = {0, 0, 0, 0};
        if ((unsigned)s < SLEN) {
            const size_t kbase = (((size_t)(b * SLEN + s) * 3 + 1) * NHEAD + h) * HD;
            const f32x4* gxl = (const f32x4*)(qkv + kbase + d0);
            const f32x4* gxh = (const f32x4*)(qkv + kbase + d0 + 32);
            const f32x4* gc  = (const f32x4*)(cosT + s * HD + d0);  // cos[d+32]==cos[d]
            const f32x4* gs  = (const f32x4*)(sinT + s * HD + d0);
            const f32x4 xl0 = gxl[0], xl1 = gxl[1];
            const f32x4 xh0 = gxh[0], xh1 = gxh[1];
            const f32x4 c0 = gc[0], c1 = gc[1];
            const f32x4 s0 = gs[0], s1 = gs[1];
            // RoPE: lo[d] = x[d]*c - x[d+32]*s ; hi[d+32] = x[d+32]*c + x[d]*s
            klo[0] = cvt_pk(xl0[0]*c0[0]-xh0[0]*s0[0], xl0[1]*c0[1]-xh0[1]*s0[1]);
            klo[1] = cvt_pk(xl0[2]*c0[2]-xh0[2]*s0[2], xl0[3]*c0[3]-xh0[3]*s0[3]);
            klo[2] = cvt_pk(xl1[0]*c1[0]-xh1[0]*s1[0], xl1[1]*c1[1]-xh1[1]*s1[1]);
            klo[3] = cvt_pk(xl1[2]*c1[2]-xh1[2]*s1[2], xl1[3]*c1[3]-xh1[3]*s1[3]);
            khi[0] = cvt_pk(xh0[0]*c0[0]+xl0[0]*s0[0], xh0[1]*c0[1]+xl0[1]*s0[1]);
            khi[1] = cvt_pk(xh0[2]*c0[2]+xl0[2]*s0[2], xh0[3]*c0[3]+xl0[3]*s0[3]);
            khi[2] = cvt_pk(xh1[0]*c1[0]+xl1[0]*s1[0], xh1[1]*c1[1]+xl1[1]*s1[1]);
            khi[3] = cvt_pk(xh1[2]*c1[2]+xl1[2]*s1[2], xh1[3]*c1[3]+xl1[3]*s1[3]);
        }
        const int sw = rr & 7;
        *(u32x4*)&sKp[rr * 64 + ((c4 ^ sw) << 3)]       = klo;
        *(u32x4*)&sKp[rr * 64 + (((c4 + 4) ^ sw) << 3)] = khi;
    }

    // ---- Q load + RoPE + pack, two half-chunks (16 regs live each) ----
    bf16x8 qf0, qf1;           // k-slots: d = g*8+j and 32+g*8+j
    {
        u32x4 w0, w1;
        const size_t qb = (((size_t)(b * SLEN + qrow) * 3 + 0) * NHEAD + h) * HD;
        #pragma unroll
        for (int p = 0; p < 2; ++p) {
            const int dq = g * 8 + p * 4;
            const f32x4 qa = *(const f32x4*)(qkv + qb + dq);
            const f32x4 qbv = *(const f32x4*)(qkv + qb + 32 + dq);
            const f32x4 qc = *(const f32x4*)(cosT + (size_t)qrow * HD + dq);
            const f32x4 qs = *(const f32x4*)(sinT + (size_t)qrow * HD + dq);
            w0[2*p]   = cvt_pk((qa[0]*qc[0]-qbv[0]*qs[0])*QSCALE,
                               (qa[1]*qc[1]-qbv[1]*qs[1])*QSCALE);
            w0[2*p+1] = cvt_pk((qa[2]*qc[2]-qbv[2]*qs[2])*QSCALE,
                               (qa[3]*qc[3]-qbv[3]*qs[3])*QSCALE);
            w1[2*p]   = cvt_pk((qbv[0]*qc[0]+qa[0]*qs[0])*QSCALE,
                               (qbv[1]*qc[1]+qa[1]*qs[1])*QSCALE);
            w1[2*p+1] = cvt_pk((qbv[2]*qc[2]+qa[2]*qs[2])*QSCALE,
                               (qbv[3]*qc[3]+qa[3]*qs[3])*QSCALE);
        }
        qf0 = __builtin_bit_cast(bf16x8, w0);
        qf1 = __builtin_bit_cast(bf16x8, w1);
    }
    __syncthreads();   // bar1: K staged

    // ===== fused QK^T -> mask -> exp -> P-pack (deferred norm) =====
    // S^T = mfma(K_chunk, Q): C row = key-in-chunk = 4g+i, C col = query = r.
    // Band mask only at kc=0 (4g+i<r) and kc=8 (4g+i>r); zero K rows give
    // score 0 -> e=1, V=0: denominator fixed analytically below.
    // paw k-slot map: key(g,j) = kb*32 + (j>>2)*16 + 4g + (j&3).
    u32x4 paw[5];
    float sum = 0.f;
    const int tg = 4 * g;
    #pragma unroll
    for (int kc = 0; kc < NKC; ++kc) {
        const int row = wv * 16 + kc * 16 + r;
        const bf16x8 ka0 = *(const bf16x8*)&sKp[row * 64 + ((g ^ rx) << 3)];
        const bf16x8 ka1 = *(const bf16x8*)&sKp[row * 64 + (((g + 4) ^ rx) << 3)];
        f32x4 c = {0.f, 0.f, 0.f, 0.f};
        c = __builtin_amdgcn_mfma_f32_16x16x32_bf16(ka0, qf0, c, 0, 0, 0);
        c = __builtin_amdgcn_mfma_f32_16x16x32_bf16(ka1, qf1, c, 0, 0, 0);
        f32x4 e;
        #pragma unroll
        for (int i = 0; i < 4; ++i) {
            float ev = exp2f(c[i]);   // scores already in log2 units
            if (kc == 0) ev = (tg + i >= r) ? ev : 0.f;
            if (kc == 8) ev = (tg + i <= r) ? ev : 0.f;
            e[i] = ev;
            sum += ev;
        }
        const uint32_t wlo = cvt_pk(e[0], e[1]);
        const uint32_t whi = cvt_pk(e[2], e[3]);
        if ((kc & 1) == 0) { paw[kc >> 1][0] = wlo; paw[kc >> 1][1] = whi; }
        else               { paw[kc >> 1][2] = wlo; paw[kc >> 1][3] = whi; }
    }
    paw[4][2] = 0; paw[4][3] = 0;

    sum += __shfl_xor(sum, 16);
    sum += __shfl_xor(sum, 32);
    const int oob = max(0, WHALF - qrow) + max(0, qrow - (SLEN - 1 - WHALF));
    const float inv = 1.f / (sum - (float)oob);

    // ---- V job-0 loads issued PRE-bar2 (no LDS touch: legal; latency
    //      hides under barrier straggler wait). 16 regs live across bar2.
    const int kp0 = tid >> 3, dd0 = (tid & 7) * 8;
    f32x4 p0a0, p0a1, p0b0, p0b1;
    {
        const int s0 = kstart + 2 * kp0, s1 = s0 + 1;
        const f32x4 z = {0.f, 0.f, 0.f, 0.f};
        p0a0 = z; p0a1 = z; p0b0 = z; p0b1 = z;
        if ((unsigned)s0 < SLEN) {
            const f32x4* g0 = (const f32x4*)(qkv +
                (((size_t)(b * SLEN + s0) * 3 + 2) * NHEAD + h) * HD + dd0);
            p0a0 = g0[0]; p0a1 = g0[1];
        }
        if ((unsigned)s1 < SLEN) {
            const f32x4* g1 = (const f32x4*)(qkv +
                (((size_t)(b * SLEN + s1) * 3 + 2) * NHEAD + h) * HD + dd0);
            p0b0 = g1[0]; p0b1 = g1[1];
        }
    }
    __syncthreads();   // bar2: all K reads done; sbuf free for V

    // ========== phase 2: V staging, 2-deep pipelined ==========
    // j1 issue -> j0 store -> j2 issue -> j1 store -> j2 store.
    {
        const int j1 = tid + 256, kp1 = j1 >> 3, dd1 = (j1 & 7) * 8;
        const int s10 = kstart + 2 * kp1, s11 = s10 + 1;
        const f32x4 z = {0.f, 0.f, 0.f, 0.f};
        f32x4 p1a0 = z, p1a1 = z, p1b0 = z, p1b1 = z;
        if ((unsigned)s10 < SLEN) {
            const f32x4* g0 = (const f32x4*)(qkv +
                (((size_t)(b * SLEN + s10) * 3 + 2) * NHEAD + h) * HD + dd1);
            p1a0 = g0[0]; p1a1 = g0[1];
        }
        if ((unsigned)s11 < SLEN) {
            const f32x4* g1 = (const f32x4*)(qkv +
                (((size_t)(b * SLEN + s11) * 3 + 2) * NHEAD + h) * HD + dd1);
            p1b0 = g1[0]; p1b1 = g1[1];
        }
        // store job 0 (its loads long in flight)
        {
            u32x4 w0, w1;
            w0[0] = cvt_pk(p0a0[0], p0b0[0]); w0[1] = cvt_pk(p0a0[1], p0b0[1]);
            w0[2] = cvt_pk(p0a0[2], p0b0[2]); w0[3] = cvt_pk(p0a0[3], p0b0[3]);
            w1[0] = cvt_pk(p0a1[0], p0b1[0]); w1[1] = cvt_pk(p0a1[1], p0b1[1]);
            w1[2] = cvt_pk(p0a1[2], p0b1[2]); w1[3] = cvt_pk(p0a1[3], p0b1[3]);
            *(u32x4*)&sbuf[kp0 * VST + dd0]     = w0;
            *(u32x4*)&sbuf[kp0 * VST + dd0 + 4] = w1;
        }
        // issue job 2
        const int j2 = tid + 512, kp2 = j2 >> 3, dd2 = (j2 & 7) * 8;
        const int s20 = kstart + 2 * kp2, s21 = s20 + 1;
        f32x4 p2a0 = z, p2a1 = z, p2b0 = z, p2b1 = z;
        if ((unsigned)s20 < SLEN) {
            const f32x4* g0 = (const f32x4*)(qkv +
                (((size_t)(b * SLEN + s20) * 3 + 2) * NHEAD + h) * HD + dd2);
            p2a0 = g0[0]; p2a1 = g0[1];
        }
        if ((unsigned)s21 < SLEN) {
            const f32x4* g1 = (const f32x4*)(qkv +
                (((size_t)(b * SLEN + s21) * 3 + 2) * NHEAD + h) * HD + dd2);
            p2b0 = g1[0]; p2b1 = g1[1];
        }
        // store job 1
        {
            u32x4 w0, w1;
            w0[0] = cvt_pk(p1a0[0], p1b0[0]); w0[1] = cvt_pk(p1a0[1], p1b0[1]);
            w0[2] = cvt_pk(p1a0[2], p1b0[2]); w0[3] = cvt_pk(p1a0[3], p1b0[3]);
            w1[0] = cvt_pk(p1a1[0], p1b1[0]); w1[1] = cvt_pk(p1a1[1], p1b1[1]);
            w1[2] = cvt_pk(p1a1[2], p1b1[2]); w1[3] = cvt_pk(p1a1[3], p1b1[3]);
            *(u32x4*)&sbuf[kp1 * VST + dd1]     = w0;
            *(u32x4*)&sbuf[kp1 * VST + dd1 + 4] = w1;
        }
        // store job 2
        {
            u32x4 w0, w1;
            w0[0] = cvt_pk(p2a0[0], p2b0[0]); w0[1] = cvt_pk(p2a0[1], p2b0[1]);
            w0[2] = cvt_pk(p2a0[2], p2b0[2]); w0[3] = cvt_pk(p2a0[3], p2b0[3]);
            w1[0] = cvt_pk(p2a1[0], p2b1[0]); w1[1] = cvt_pk(p2a1[1], p2b1[1]);
            w1[2] = cvt_pk(p2a1[2], p2b1[2]); w1[3] = cvt_pk(p2a1[3], p2b1[3]);
            *(u32x4*)&sbuf[kp2 * VST + dd2]     = w0;
            *(u32x4*)&sbuf[kp2 * VST + dd2 + 4] = w1;
        }
    }
    __syncthreads();   // bar3: V staged

    // ================= O = P x V (paired-key u32 reads) =================
    // kb<4: keys kb*32 + {0,1,2,3,16,17,18,19} + 4g (pairs +0,+1,+8,+9).
    // kb=4: lo half only (hi pa==0 -> w[2]=w[3]=0, no LDS read; max kp=95).
    const uint32_t* vptr = &sbuf[(wv * 8 + 2 * g) * VST + r];
    f32x4 oacc[4] = {{0,0,0,0},{0,0,0,0},{0,0,0,0},{0,0,0,0}};
    #pragma unroll
    for (int kb = 0; kb < 5; ++kb) {
        const bf16x8 pa = __builtin_bit_cast(bf16x8, paw[kb]);
        #pragma unroll
        for (int dc = 0; dc < 4; ++dc) {
            const int base = kb * 16 * VST + dc * 16;
            u32x4 w;
            w[0] = vptr[base];                 // keys kb*32+4g, +1
            w[1] = vptr[base + VST];           // +2, +3
            if (kb < 4) {
                w[2] = vptr[base + 8 * VST];   // +16, +17
                w[3] = vptr[base + 9 * VST];   // +18, +19
            } else {
                w[2] = 0; w[3] = 0;            // pa hi == 0; avoid OOB read
            }
            const bf16x8 vbf = __builtin_bit_cast(bf16x8, w);
            oacc[dc] = __builtin_amdgcn_mfma_f32_16x16x32_bf16(pa, vbf, oacc[dc], 0, 0, 0);
        }
    }

    // ---- store (C row = query = g*4+i, col = d = r), deferred norm ----
    #pragma unroll
    for (int i = 0; i < 4; ++i) {
        const float iq = __shfl(inv, g * 4 + i);   // inv depends only on lane&15
        const int qg = q0 + wv * 16 + g * 4 + i;
        float* orow = out + (((size_t)(b * SLEN + qg)) * NHEAD + h) * HD + r;
        orow[0]  = oacc[0][i] * iq;
        orow[16] = oacc[1][i] * iq;
        orow[32] = oacc[2][i] * iq;
        orow[48] = oacc[3][i] * iq;
    }
}

extern "C" void kernel_launch(void* const* d_in, const int* in_sizes, int n_in,
                              void* d_out, int out_size, void* d_ws, size_t ws_size,
                              hipStream_t stream) {
    const float* qkv  = (const float*)d_in[0];
    const float* cosT = (const float*)d_in[1];
    const float* sinT = (const float*)d_in[2];
    // d_in[3] = mask: unused (band structure computed analytically)
    float* out = (float*)d_out;
    dim3 grid(32 * NHEAD * NBATCH);   // 1536 = 6 blocks/CU x 256 CUs, no tail
    dim3 block(256);
    hipLaunchKernelGGL(prokbert_attn, grid, block, 0, stream, qkv, cosT, sinT, out);
}

// Round 18
// 26.677 us; speedup vs baseline: 1.0385x; 1.0385x over previous
//
#include <hip/hip_runtime.h>
#include <hip/hip_bf16.h>
#include <cstdint>

// ProkBertAttention: sliding-window (+-64) attention with RoPE.
// B=4, S=2048, H=12, D=64. fp32 in/out, bf16 MFMA compute.
// Mask input (d_in[3]) ignored: band structure computed analytically.
//
// Round 18 = round 16 (best: 26.62us) with launch_bounds (256,8)->(256,7).
// Rationale: LDS (26,112B -> 6 blocks/CU = 24 waves = 6 waves/SIMD) is the
// binding occupancy limit, NOT VGPR; the (256,8) 64-reg cap bought nothing
// above 6 waves/SIMD but forced strictly-serial staging (one ~900cyc load
// stall per job). Cap 73 (=512/7) keeps 7 waves/SIMD >= 6 (zero occupancy
// loss) and gives the compiler ~9 regs to batch staging loads itself.
// r17's HAND-rolled 2-deep V pipeline regressed (27.70) -> reverted; this
// delegates the same idea to the register allocator instead.
// Ledger: r16 26.62 (best); r12 27.20; r17 V-pipeline 27.70; setprio
// neutral (r15); decomposition 35.3 (r14); (256,6) mis-compiles (r8/r11,
// signature: VGPR~40 + WRITE >> 24.6MB).

typedef short bf16x8 __attribute__((ext_vector_type(8)));
typedef float f32x4  __attribute__((ext_vector_type(4)));
typedef uint32_t u32x4 __attribute__((ext_vector_type(4)));

#define SLEN   2048
#define NHEAD  12
#define NBATCH 4
#define HD     64
#define WHALF  64
#define QT     64          // queries per block (4 waves x 16)
#define KROWS  192         // QT + 2*WHALF
#define NKC    9           // per-wave key chunks (144-key span)
#define VST    68          // V-pair row stride in dwords
#define VROWS  96          // key-pairs (max kp read = 95: kb=4 lo-only)
// scale * log2(e) = (1/8) * 1.4426950408889634 (scores in log2 units)
#define QSCALE 0.18033688011112042f

// Phase 1: sbuf holds K bf16 [192][64] (24,576 B), 16B-chunk XOR (c^(rr&7)).
// Phase 2: sbuf holds V key-paired u32 [96][68] (26,112 B), cell[kp][d] =
//          (bf16 V[2kp][d], V[2kp+1][d]).
// LDS alloc = 26,112 B; 6 blocks/CU (156,672 <= 163,840); VGPR cap 73.

__device__ __forceinline__ uint32_t cvt_pk(float lo, float hi) {
    // dst[15:0] = bf16(lo), dst[31:16] = bf16(hi); RNE (gfx950)
    uint32_t r;
    asm("v_cvt_pk_bf16_f32 %0, %1, %2" : "=v"(r) : "v"(lo), "v"(hi));
    return r;
}

__global__ __launch_bounds__(256, 7) void prokbert_attn(
        const float* __restrict__ qkv, const float* __restrict__ cosT,
        const float* __restrict__ sinT, float* __restrict__ out)
{
    __shared__ __align__(16) uint32_t sbuf[VROWS * VST];
    short* sKp = (short*)sbuf;

    const int tid = threadIdx.x;

    // ---- XCD-aware block swizzle (1536 blocks = 8 XCDs x 192, bijective) ----
    const int bid = blockIdx.x;
    const int gid = (bid & 7) * 192 + (bid >> 3);
    const int qt = gid & 31;          // 32 q-tiles per (b,h)
    const int hh = gid >> 5;          // 0..47 = b*12 + h
    const int h = hh % NHEAD, b = hh / NHEAD;

    const int q0 = qt * QT;
    const int kstart = q0 - WHALF;

    const int wv = tid >> 6;
    const int lane = tid & 63;
    const int r = lane & 15, g = lane >> 4;
    const int rx = r & 7;
    const int qrow = q0 + wv * 16 + r;

    // ========== phase 1: K staging, 3 jobs (compiler-scheduled) ==========
    // job (rr, c4) owns d = c4*8..+7 AND +32; rr = rrb + it*64.
    const int rrb = tid >> 2, c4 = tid & 3, d0 = c4 * 8;

    #pragma unroll
    for (int it = 0; it < 3; ++it) {
        const int rr = rrb + it * 64;
        const int s = kstart + rr;
        u32x4 klo = {0, 0, 0, 0}, khi = {0, 0, 0, 0};
        if ((unsigned)s < SLEN) {
            const size_t kbase = (((size_t)(b * SLEN + s) * 3 + 1) * NHEAD + h) * HD;
            const f32x4* gxl = (const f32x4*)(qkv + kbase + d0);
            const f32x4* gxh = (const f32x4*)(qkv + kbase + d0 + 32);
            const f32x4* gc  = (const f32x4*)(cosT + s * HD + d0);  // cos[d+32]==cos[d]
            const f32x4* gs  = (const f32x4*)(sinT + s * HD + d0);
            const f32x4 xl0 = gxl[0], xl1 = gxl[1];
            const f32x4 xh0 = gxh[0], xh1 = gxh[1];
            const f32x4 c0 = gc[0], c1 = gc[1];
            const f32x4 s0 = gs[0], s1 = gs[1];
            // RoPE: lo[d] = x[d]*c - x[d+32]*s ; hi[d+32] = x[d+32]*c + x[d]*s
            klo[0] = cvt_pk(xl0[0]*c0[0]-xh0[0]*s0[0], xl0[1]*c0[1]-xh0[1]*s0[1]);
            klo[1] = cvt_pk(xl0[2]*c0[2]-xh0[2]*s0[2], xl0[3]*c0[3]-xh0[3]*s0[3]);
            klo[2] = cvt_pk(xl1[0]*c1[0]-xh1[0]*s1[0], xl1[1]*c1[1]-xh1[1]*s1[1]);
            klo[3] = cvt_pk(xl1[2]*c1[2]-xh1[2]*s1[2], xl1[3]*c1[3]-xh1[3]*s1[3]);
            khi[0] = cvt_pk(xh0[0]*c0[0]+xl0[0]*s0[0], xh0[1]*c0[1]+xl0[1]*s0[1]);
            khi[1] = cvt_pk(xh0[2]*c0[2]+xl0[2]*s0[2], xh0[3]*c0[3]+xl0[3]*s0[3]);
            khi[2] = cvt_pk(xh1[0]*c1[0]+xl1[0]*s1[0], xh1[1]*c1[1]+xl1[1]*s1[1]);
            khi[3] = cvt_pk(xh1[2]*c1[2]+xl1[2]*s1[2], xh1[3]*c1[3]+xl1[3]*s1[3]);
        }
        const int sw = rr & 7;
        *(u32x4*)&sKp[rr * 64 + ((c4 ^ sw) << 3)]       = klo;
        *(u32x4*)&sKp[rr * 64 + (((c4 + 4) ^ sw) << 3)] = khi;
    }

    // ---- Q load + RoPE + pack, two half-chunks ----
    bf16x8 qf0, qf1;           // k-slots: d = g*8+j and 32+g*8+j
    {
        u32x4 w0, w1;
        const size_t qb = (((size_t)(b * SLEN + qrow) * 3 + 0) * NHEAD + h) * HD;
        #pragma unroll
        for (int p = 0; p < 2; ++p) {
            const int dq = g * 8 + p * 4;
            const f32x4 qa = *(const f32x4*)(qkv + qb + dq);
            const f32x4 qbv = *(const f32x4*)(qkv + qb + 32 + dq);
            const f32x4 qc = *(const f32x4*)(cosT + (size_t)qrow * HD + dq);
            const f32x4 qs = *(const f32x4*)(sinT + (size_t)qrow * HD + dq);
            w0[2*p]   = cvt_pk((qa[0]*qc[0]-qbv[0]*qs[0])*QSCALE,
                               (qa[1]*qc[1]-qbv[1]*qs[1])*QSCALE);
            w0[2*p+1] = cvt_pk((qa[2]*qc[2]-qbv[2]*qs[2])*QSCALE,
                               (qa[3]*qc[3]-qbv[3]*qs[3])*QSCALE);
            w1[2*p]   = cvt_pk((qbv[0]*qc[0]+qa[0]*qs[0])*QSCALE,
                               (qbv[1]*qc[1]+qa[1]*qs[1])*QSCALE);
            w1[2*p+1] = cvt_pk((qbv[2]*qc[2]+qa[2]*qs[2])*QSCALE,
                               (qbv[3]*qc[3]+qa[3]*qs[3])*QSCALE);
        }
        qf0 = __builtin_bit_cast(bf16x8, w0);
        qf1 = __builtin_bit_cast(bf16x8, w1);
    }
    __syncthreads();   // bar1: K staged

    // ===== fused QK^T -> mask -> exp -> P-pack (deferred norm) =====
    // S^T = mfma(K_chunk, Q): C row = key-in-chunk = 4g+i, C col = query = r.
    // Band mask only at kc=0 (4g+i<r) and kc=8 (4g+i>r); zero K rows give
    // score 0 -> e=1, V=0: denominator fixed analytically below.
    // paw k-slot map: key(g,j) = kb*32 + (j>>2)*16 + 4g + (j&3).
    u32x4 paw[5];
    float sum = 0.f;
    const int tg = 4 * g;
    #pragma unroll
    for (int kc = 0; kc < NKC; ++kc) {
        const int row = wv * 16 + kc * 16 + r;
        const bf16x8 ka0 = *(const bf16x8*)&sKp[row * 64 + ((g ^ rx) << 3)];
        const bf16x8 ka1 = *(const bf16x8*)&sKp[row * 64 + (((g + 4) ^ rx) << 3)];
        f32x4 c = {0.f, 0.f, 0.f, 0.f};
        c = __builtin_amdgcn_mfma_f32_16x16x32_bf16(ka0, qf0, c, 0, 0, 0);
        c = __builtin_amdgcn_mfma_f32_16x16x32_bf16(ka1, qf1, c, 0, 0, 0);
        f32x4 e;
        #pragma unroll
        for (int i = 0; i < 4; ++i) {
            float ev = exp2f(c[i]);   // scores already in log2 units
            if (kc == 0) ev = (tg + i >= r) ? ev : 0.f;
            if (kc == 8) ev = (tg + i <= r) ? ev : 0.f;
            e[i] = ev;
            sum += ev;
        }
        const uint32_t wlo = cvt_pk(e[0], e[1]);
        const uint32_t whi = cvt_pk(e[2], e[3]);
        if ((kc & 1) == 0) { paw[kc >> 1][0] = wlo; paw[kc >> 1][1] = whi; }
        else               { paw[kc >> 1][2] = wlo; paw[kc >> 1][3] = whi; }
    }
    paw[4][2] = 0; paw[4][3] = 0;

    sum += __shfl_xor(sum, 16);
    sum += __shfl_xor(sum, 32);
    const int oob = max(0, WHALF - qrow) + max(0, qrow - (SLEN - 1 - WHALF));
    const float inv = 1.f / (sum - (float)oob);

    __syncthreads();   // bar2: all K reads done; sbuf free for V

    // ========== phase 2: V staging, 3 jobs (compiler-scheduled) ==========
    // job j = tid + it*256: kp = j>>3 in [0,96), c8 = j&7 -> d = c8*8..+7.
    #pragma unroll
    for (int it = 0; it < 3; ++it) {
        const int j = tid + it * 256;
        const int kp = j >> 3, dd = (j & 7) * 8;
        const int s0 = kstart + 2 * kp, s1 = s0 + 1;
        const f32x4 z = {0.f, 0.f, 0.f, 0.f};
        f32x4 va0 = z, va1 = z, vb0 = z, vb1 = z;
        if ((unsigned)s0 < SLEN) {
            const f32x4* g0 = (const f32x4*)(qkv +
                (((size_t)(b * SLEN + s0) * 3 + 2) * NHEAD + h) * HD + dd);
            va0 = g0[0]; va1 = g0[1];
        }
        if ((unsigned)s1 < SLEN) {
            const f32x4* g1 = (const f32x4*)(qkv +
                (((size_t)(b * SLEN + s1) * 3 + 2) * NHEAD + h) * HD + dd);
            vb0 = g1[0]; vb1 = g1[1];
        }
        u32x4 w0, w1;
        w0[0] = cvt_pk(va0[0], vb0[0]); w0[1] = cvt_pk(va0[1], vb0[1]);
        w0[2] = cvt_pk(va0[2], vb0[2]); w0[3] = cvt_pk(va0[3], vb0[3]);
        w1[0] = cvt_pk(va1[0], vb1[0]); w1[1] = cvt_pk(va1[1], vb1[1]);
        w1[2] = cvt_pk(va1[2], vb1[2]); w1[3] = cvt_pk(va1[3], vb1[3]);
        *(u32x4*)&sbuf[kp * VST + dd]     = w0;
        *(u32x4*)&sbuf[kp * VST + dd + 4] = w1;
    }
    __syncthreads();   // bar3: V staged

    // ================= O = P x V (paired-key u32 reads) =================
    // kb<4: keys kb*32 + {0,1,2,3,16,17,18,19} + 4g (pairs +0,+1,+8,+9).
    // kb=4: lo half only (hi pa==0 -> w[2]=w[3]=0, no LDS read; max kp=95).
    const uint32_t* vptr = &sbuf[(wv * 8 + 2 * g) * VST + r];
    f32x4 oacc[4] = {{0,0,0,0},{0,0,0,0},{0,0,0,0},{0,0,0,0}};
    #pragma unroll
    for (int kb = 0; kb < 5; ++kb) {
        const bf16x8 pa = __builtin_bit_cast(bf16x8, paw[kb]);
        #pragma unroll
        for (int dc = 0; dc < 4; ++dc) {
            const int base = kb * 16 * VST + dc * 16;
            u32x4 w;
            w[0] = vptr[base];                 // keys kb*32+4g, +1
            w[1] = vptr[base + VST];           // +2, +3
            if (kb < 4) {
                w[2] = vptr[base + 8 * VST];   // +16, +17
                w[3] = vptr[base + 9 * VST];   // +18, +19
            } else {
                w[2] = 0; w[3] = 0;            // pa hi == 0; avoid OOB read
            }
            const bf16x8 vbf = __builtin_bit_cast(bf16x8, w);
            oacc[dc] = __builtin_amdgcn_mfma_f32_16x16x32_bf16(pa, vbf, oacc[dc], 0, 0, 0);
        }
    }

    // ---- store (C row = query = g*4+i, col = d = r), deferred norm ----
    #pragma unroll
    for (int i = 0; i < 4; ++i) {
        const float iq = __shfl(inv, g * 4 + i);   // inv depends only on lane&15
        const int qg = q0 + wv * 16 + g * 4 + i;
        float* orow = out + (((size_t)(b * SLEN + qg)) * NHEAD + h) * HD + r;
        orow[0]  = oacc[0][i] * iq;
        orow[16] = oacc[1][i] * iq;
        orow[32] = oacc[2][i] * iq;
        orow[48] = oacc[3][i] * iq;
    }
}

extern "C" void kernel_launch(void* const* d_in, const int* in_sizes, int n_in,
                              void* d_out, int out_size, void* d_ws, size_t ws_size,
                              hipStream_t stream) {
    const float* qkv  = (const float*)d_in[0];
    const float* cosT = (const float*)d_in[1];
    const float* sinT = (const float*)d_in[2];
    // d_in[3] = mask: unused (band structure computed analytically)
    float* out = (float*)d_out;
    dim3 grid(32 * NHEAD * NBATCH);   // 1536 = 6 blocks/CU x 256 CUs, no tail
    dim3 block(256);
    hipLaunchKernelGGL(prokbert_attn, grid, block, 0, stream, qkv, cosT, sinT, out);
}